// Round 5
// baseline (446.138 us; speedup 1.0000x reference)
//
#include <hip/hip_runtime.h>
#include <math.h>

// Problem: B=4, S=8192, H=2048, K=4, fp32. Causal depthwise conv + SiLU.
#define CB 4
#define CS 8192
#define CH 2048
#define CH4 (CH / 4)          // 512 float4 groups per row
#define TT 32                 // timesteps per thread (halo 3/32 = 9.4%)
#define TSTRIPS (CS / TT)     // 256

typedef float f4 __attribute__((ext_vector_type(4)));

__device__ __forceinline__ f4 silu4(f4 v) {
    f4 r;
    r.x = v.x * __builtin_amdgcn_rcpf(1.0f + __expf(-v.x));
    r.y = v.y * __builtin_amdgcn_rcpf(1.0f + __expf(-v.y));
    r.z = v.z * __builtin_amdgcn_rcpf(1.0f + __expf(-v.z));
    r.w = v.w * __builtin_amdgcn_rcpf(1.0f + __expf(-v.w));
    return r;
}

__device__ __forceinline__ f4 conv4(f4 w0, f4 w1, f4 w2, f4 w3,
                                    f4 m3, f4 m2, f4 m1, f4 c) {
    f4 o;
    o.x = w0.x * m3.x + w0.y * m2.x + w0.z * m1.x + w0.w * c.x;
    o.y = w1.x * m3.y + w1.y * m2.y + w1.z * m1.y + w1.w * c.y;
    o.z = w2.x * m3.z + w2.y * m2.z + w2.z * m1.z + w2.w * c.z;
    o.w = w3.x * m3.w + w3.y * m2.w + w3.z * m1.w + w3.w * c.w;
    return o;
}

// Triple-buffered 4-row software pipeline at low VGPR for high occupancy.
// Rotation A/B/C: a body is loaded, rests one full body, then computed —
// load-to-use distance ~2 body-periods. Body n's rows t-3..t-1 are read
// straight from body n-1's buffer tail (no carry registers), legal because
// with 3 buffers the previous body is not overwritten until after use.
// sched_barrier(0) pins each LOAD/COMP region in program order.
__global__ __launch_bounds__(256, 6) void dwconv_silu_kernel(
        const float* __restrict__ x,
        const float* __restrict__ w,
        float* __restrict__ y) {
    const int tid = blockIdx.x * 256 + threadIdx.x;
    const int h4 = tid & (CH4 - 1);          // consecutive lanes -> coalesced float4 in H
    const int strip = tid >> 9;              // tid / 512
    const int b = strip >> 8;                // / TSTRIPS
    const int t0 = (strip & (TSTRIPS - 1)) * TT;

    const f4* __restrict__ xp = (const f4*)x + (size_t)b * CS * CH4 + h4 + (size_t)t0 * CH4;
    f4* __restrict__ yp = (f4*)y + (size_t)b * CS * CH4 + h4 + (size_t)t0 * CH4;

    // Weight taps for channels 4*h4 .. 4*h4+3.
    const f4* __restrict__ wv = (const f4*)w + (size_t)h4 * 4;
    const f4 w0 = wv[0], w1 = wv[1], w2 = wv[2], w3 = wv[3];

    f4 a0, a1, a2, a3, b0, b1, b2, b3, c0, c1, c2, c3;

    // Halo rows t0-3..t0-1 into C tail (zero at sequence start; t0 is
    // uniform per block so the branch is wave-uniform).
    c1 = 0.f; c2 = 0.f; c3 = 0.f;
    if (t0 != 0) {
        c1 = xp[-3 * CH4];
        c2 = xp[-2 * CH4];
        c3 = xp[-1 * CH4];
    }

#define LOAD4(P0, P1, P2, P3)                                              \
    P0 = xp[0 * CH4];                                                      \
    P1 = xp[1 * CH4];                                                      \
    P2 = xp[2 * CH4];                                                      \
    P3 = xp[3 * CH4];                                                      \
    xp += 4 * CH4;                                                         \
    __builtin_amdgcn_sched_barrier(0);

    // Q1,Q2,Q3 = rows t-3..t-1 (tail of the previous body's buffer).
#define COMP4(P0, P1, P2, P3, Q1, Q2, Q3)                                  \
    __builtin_nontemporal_store(silu4(conv4(w0, w1, w2, w3, Q1, Q2, Q3, P0)), yp + 0 * CH4); \
    __builtin_nontemporal_store(silu4(conv4(w0, w1, w2, w3, Q2, Q3, P0, P1)), yp + 1 * CH4); \
    __builtin_nontemporal_store(silu4(conv4(w0, w1, w2, w3, Q3, P0, P1, P2)), yp + 2 * CH4); \
    __builtin_nontemporal_store(silu4(conv4(w0, w1, w2, w3, P0, P1, P2, P3)), yp + 3 * CH4); \
    yp += 4 * CH4;                                                         \
    __builtin_amdgcn_sched_barrier(0);

    // TT=32 -> 8 bodies. Fully unrolled 3-phase rotation.
    LOAD4(a0, a1, a2, a3)                 // body 0
    LOAD4(b0, b1, b2, b3)                 // body 1
    COMP4(a0, a1, a2, a3, c1, c2, c3)     // body 0 (prev = halo in C tail)
    LOAD4(c0, c1, c2, c3)                 // body 2
    COMP4(b0, b1, b2, b3, a1, a2, a3)     // body 1
    LOAD4(a0, a1, a2, a3)                 // body 3
    COMP4(c0, c1, c2, c3, b1, b2, b3)     // body 2
    LOAD4(b0, b1, b2, b3)                 // body 4
    COMP4(a0, a1, a2, a3, c1, c2, c3)     // body 3
    LOAD4(c0, c1, c2, c3)                 // body 5
    COMP4(b0, b1, b2, b3, a1, a2, a3)     // body 4
    LOAD4(a0, a1, a2, a3)                 // body 6
    COMP4(c0, c1, c2, c3, b1, b2, b3)     // body 5
    LOAD4(b0, b1, b2, b3)                 // body 7
    COMP4(a0, a1, a2, a3, c1, c2, c3)     // body 6
    COMP4(b0, b1, b2, b3, a1, a2, a3)     // body 7

#undef LOAD4
#undef COMP4
}

extern "C" void kernel_launch(void* const* d_in, const int* in_sizes, int n_in,
                              void* d_out, int out_size, void* d_ws, size_t ws_size,
                              hipStream_t stream) {
    const float* x = (const float*)d_in[0];   // (B, S, H) fp32
    const float* w = (const float*)d_in[1];   // (H, K) fp32
    float* y = (float*)d_out;                 // (B, S, H) fp32

    const int total_threads = CB * TSTRIPS * CH4;    // 4 * 256 * 512 = 524288
    dwconv_silu_kernel<<<total_threads / 256, 256, 0, stream>>>(x, w, y);
}

// Round 6
// 430.249 us; speedup vs baseline: 1.0369x; 1.0369x over previous
//
#include <hip/hip_runtime.h>
#include <math.h>

// Problem: B=4, S=8192, H=2048, K=4, fp32. Causal depthwise conv + SiLU.
// R6 = R1's exact structure (best so far, ~140us dispatch: NT loads + NT
// stores + rolling window + natural compiler schedule), with TT halved to
// double the grid: 2048 blocks = 8 blocks/CU -> up to 32 resident waves/CU
// (was grid-capped at 16). Single-variable change targeting read-side TLP.
#define CB 4
#define CS 8192
#define CH 2048
#define CH4 (CH / 4)      // 512 float4 groups per row
#define TT 32             // timesteps per thread (halo 3/32 = 9.4%)
#define TSTRIPS (CS / TT) // 256

typedef float f4 __attribute__((ext_vector_type(4)));

__device__ __forceinline__ float silu_fast(float v) {
    return v * __builtin_amdgcn_rcpf(1.0f + __expf(-v));
}

__global__ __launch_bounds__(256) void dwconv_silu_kernel(
        const float* __restrict__ x,
        const float* __restrict__ w,
        float* __restrict__ y) {
    const int tid = blockIdx.x * 256 + threadIdx.x;
    const int h4 = tid & (CH4 - 1);          // consecutive lanes -> coalesced float4 in H
    const int strip = tid >> 9;              // tid / 512
    const int b = strip >> 8;                // / TSTRIPS
    const int t0 = (strip & (TSTRIPS - 1)) * TT;

    const f4* __restrict__ xb = reinterpret_cast<const f4*>(x) + (size_t)b * CS * CH4 + h4;
    f4* __restrict__ yb = reinterpret_cast<f4*>(y) + (size_t)b * CS * CH4 + h4;

    // Weight taps for channels 4*h4 .. 4*h4+3.
    const f4* __restrict__ wv = reinterpret_cast<const f4*>(w) + (size_t)h4 * 4;
    const f4 wr0 = wv[0];
    const f4 wr1 = wv[1];
    const f4 wr2 = wv[2];
    const f4 wr3 = wv[3];

    // Sliding window rows t0-3..t0-1 (zero-padded at sequence start; t0 is
    // uniform per block so the branch is wave-uniform).
    f4 xm3 = 0.f, xm2 = 0.f, xm1 = 0.f;
    if (t0 != 0) {
        const f4* hp = xb + (size_t)(t0 - 3) * CH4;
        xm3 = __builtin_nontemporal_load(hp);
        xm2 = __builtin_nontemporal_load(hp + CH4);
        xm1 = __builtin_nontemporal_load(hp + 2 * CH4);
    }

    const f4* __restrict__ xp = xb + (size_t)t0 * CH4;
    f4* __restrict__ yp = yb + (size_t)t0 * CH4;

    #pragma unroll 8
    for (int i = 0; i < TT; ++i) {
        const f4 cur = __builtin_nontemporal_load(xp);

        f4 o;
        o.x = wr0.x * xm3.x + wr0.y * xm2.x + wr0.z * xm1.x + wr0.w * cur.x;
        o.y = wr1.x * xm3.y + wr1.y * xm2.y + wr1.z * xm1.y + wr1.w * cur.y;
        o.z = wr2.x * xm3.z + wr2.y * xm2.z + wr2.z * xm1.z + wr2.w * cur.z;
        o.w = wr3.x * xm3.w + wr3.y * xm2.w + wr3.z * xm1.w + wr3.w * cur.w;

        o.x = silu_fast(o.x);
        o.y = silu_fast(o.y);
        o.z = silu_fast(o.z);
        o.w = silu_fast(o.w);

        __builtin_nontemporal_store(o, yp);

        xm3 = xm2;
        xm2 = xm1;
        xm1 = cur;
        xp += CH4;
        yp += CH4;
    }
}

extern "C" void kernel_launch(void* const* d_in, const int* in_sizes, int n_in,
                              void* d_out, int out_size, void* d_ws, size_t ws_size,
                              hipStream_t stream) {
    const float* x = (const float*)d_in[0];   // (B, S, H) fp32
    const float* w = (const float*)d_in[1];   // (H, K) fp32
    float* y = (float*)d_out;                 // (B, S, H) fp32

    const int total_threads = CB * TSTRIPS * CH4;    // 4 * 256 * 512 = 524288
    dwconv_silu_kernel<<<total_threads / 256, 256, 0, stream>>>(x, w, y);
}